// Round 1
// baseline (1624.163 us; speedup 1.0000x reference)
//
#include <hip/hip_runtime.h>
#include <hip/hip_bf16.h>
#include <math.h>

#define B_ 2
#define T_ 2048
#define DIM_ 1024
#define H_ 16
#define HD_ 64
#define NROWS_ (B_*T_)
#define PR 8

__device__ __forceinline__ float wave_sum64(float v) {
#pragma unroll
  for (int off = 32; off > 0; off >>= 1) v += __shfl_xor(v, off, 64);
  return v;
}

// ---------------- K1: fused QKV projection ----------------
// grid = NROWS_/PR blocks, 256 threads (4 waves). Each block stages PR=8 rows
// of x in LDS; each wave computes one output column (of 1152) for all 8 rows
// via a 64-lane cooperative dot + butterfly reduce.
__global__ __launch_bounds__(256) void qkv_kernel(
    const float* __restrict__ x, const float* __restrict__ wq,
    const float* __restrict__ wk, const float* __restrict__ wv,
    float* __restrict__ q, float* __restrict__ k, float* __restrict__ v) {
  __shared__ float xs[PR][DIM_];
  const int tid = threadIdx.x;
  const int row0 = blockIdx.x * PR;
  {
    const float4* src = (const float4*)(x + (size_t)row0 * DIM_);
    float4* dst = (float4*)&xs[0][0];
#pragma unroll
    for (int j = 0; j < (PR * DIM_ / 4) / 256; ++j)
      dst[tid + 256 * j] = src[tid + 256 * j];
  }
  __syncthreads();
  const int wave = tid >> 6, lane = tid & 63;
  for (int u = wave; u < DIM_ + 2 * HD_; u += 4) {
    const float* wrow;
    if (u < DIM_) wrow = wq + (size_t)u * DIM_;
    else if (u < DIM_ + HD_) wrow = wk + (size_t)(u - DIM_) * DIM_;
    else wrow = wv + (size_t)(u - DIM_ - HD_) * DIM_;
    const float4* w4 = (const float4*)wrow;
    float acc[PR];
#pragma unroll
    for (int r = 0; r < PR; ++r) acc[r] = 0.f;
#pragma unroll
    for (int j = 0; j < DIM_ / 4 / 64; ++j) {  // 4 iters
      float4 wv4 = w4[lane + 64 * j];
#pragma unroll
      for (int r = 0; r < PR; ++r) {
        float4 xv = ((const float4*)&xs[r][0])[lane + 64 * j];
        acc[r] = fmaf(wv4.x, xv.x, acc[r]);
        acc[r] = fmaf(wv4.y, xv.y, acc[r]);
        acc[r] = fmaf(wv4.z, xv.z, acc[r]);
        acc[r] = fmaf(wv4.w, xv.w, acc[r]);
      }
    }
#pragma unroll
    for (int r = 0; r < PR; ++r) acc[r] = wave_sum64(acc[r]);
    if (lane == 0) {
#pragma unroll
      for (int r = 0; r < PR; ++r) {
        int row = row0 + r;
        if (u < DIM_) q[(size_t)row * DIM_ + u] = acc[r];
        else if (u < DIM_ + HD_) k[(size_t)row * HD_ + (u - DIM_)] = acc[r];
        else v[(size_t)row * HD_ + (u - DIM_ - HD_)] = acc[r];
      }
    }
  }
}

// ---------------- K2: RMSNorm + RoPE (in-place) ----------------
// grid = NROWS_ blocks of 64 threads. Each block handles one (b,t) row:
// 16 q-heads + 1 k-head, each a 64-wide rmsnorm + rope pair rotation.
__global__ __launch_bounds__(64) void normrope_kernel(
    float* __restrict__ q, float* __restrict__ k,
    const float* __restrict__ qg, const float* __restrict__ kg,
    const float* __restrict__ fc, const float* __restrict__ fs) {
  const int row = blockIdx.x;
  const int t = row & (T_ - 1);
  const int d = threadIdx.x;
  const float c = fc[t * (HD_ / 2) + (d >> 1)];
  const float s = fs[t * (HD_ / 2) + (d >> 1)];
  for (int hh = 0; hh < H_ + 1; ++hh) {
    float* ptr;
    float g;
    if (hh < H_) { ptr = q + (size_t)row * DIM_ + hh * HD_; g = qg[d]; }
    else         { ptr = k + (size_t)row * HD_;             g = kg[d]; }
    float val = ptr[d];
    float ssum = wave_sum64(val * val);
    float rms = rsqrtf(ssum * (1.f / HD_) + 1e-6f);
    val = val * rms * g;
    float partner = __shfl_xor(val, 1, 64);
    float res = ((d & 1) == 0) ? (val * c - partner * s) : (partner * s + val * c);
    ptr[d] = res;
  }
}

// ---------------- K3: flash-style causal attention with tanh softcap ----------------
// grid (T/64, H, B), 256 threads. Thread tid owns query row r = tid>>2 of the
// 64-row Q tile and quarter p = tid&3 (16 score columns c = p+4*cc, 16 output
// dims p*16..p*16+15). Online softmax state (m,l) replicated in the 4-lane
// row group via xor-shuffles. LDS rows padded to 68 floats: score K-reads and
// PV V-reads are <=2-way bank conflicts (free).
#define PADF 68
__global__ __launch_bounds__(256) void attn_kernel(
    const float* __restrict__ q, const float* __restrict__ k,
    const float* __restrict__ v, float* __restrict__ att) {
  __shared__ float Qs[64 * PADF];
  __shared__ float Ks[64 * PADF];
  __shared__ float Vs[64 * PADF];
  __shared__ float Ps[64 * PADF];
  const int tid = threadIdx.x;
  const int qtile = blockIdx.x;
  const int h = blockIdx.y;
  const int b = blockIdx.z;
  const int qt0 = qtile * 64;
  // load Q tile (row stride in global = H_*HD_)
  const float* qbase = q + ((size_t)(b * T_ + qt0) * H_ + h) * HD_;
  for (int t2 = tid; t2 < 64 * 16; t2 += 256) {
    int rr = t2 >> 4, d4 = t2 & 15;
    ((float4*)Qs)[rr * (PADF / 4) + d4] =
        ((const float4*)(qbase + (size_t)rr * (H_ * HD_)))[d4];
  }
  const int r = tid >> 2, p = tid & 3;
  float m = -INFINITY, l = 0.f;
  float acc[16];
#pragma unroll
  for (int i = 0; i < 16; ++i) acc[i] = 0.f;

  for (int ct = 0; ct <= qtile; ++ct) {
    const int c0 = ct * 64;
    __syncthreads();  // previous PV done before overwriting K/V
    const float* kb = k + (size_t)(b * T_ + c0) * HD_;
    const float* vb = v + (size_t)(b * T_ + c0) * HD_;
    for (int t2 = tid; t2 < 64 * 16; t2 += 256) {
      int rr = t2 >> 4, d4 = t2 & 15;
      ((float4*)Ks)[rr * (PADF / 4) + d4] = ((const float4*)kb)[rr * 16 + d4];
      ((float4*)Vs)[rr * (PADF / 4) + d4] = ((const float4*)vb)[rr * 16 + d4];
    }
    __syncthreads();
    // scores: 16 columns per thread
    float sc[16];
#pragma unroll
    for (int cc = 0; cc < 16; ++cc) sc[cc] = 0.f;
#pragma unroll 4
    for (int d4 = 0; d4 < 16; ++d4) {
      float4 q4 = ((const float4*)Qs)[r * (PADF / 4) + d4];
#pragma unroll
      for (int cc = 0; cc < 16; ++cc) {
        int c = p + 4 * cc;
        float4 k4 = ((const float4*)Ks)[c * (PADF / 4) + d4];
        sc[cc] = fmaf(q4.x, k4.x, sc[cc]);
        sc[cc] = fmaf(q4.y, k4.y, sc[cc]);
        sc[cc] = fmaf(q4.z, k4.z, sc[cc]);
        sc[cc] = fmaf(q4.w, k4.w, sc[cc]);
      }
    }
    // softcap: 50*tanh(dot*0.125/50) = 50 - 100/(exp(dot*0.005)+1)
    float mtile = -INFINITY;
#pragma unroll
    for (int cc = 0; cc < 16; ++cc) {
      int cidx = c0 + p + 4 * cc;
      float E = __expf(sc[cc] * (2.f * 0.125f / 50.f));
      float capped = 50.f - 100.f / (E + 1.f);
      bool valid = (cidx <= qt0 + r);
      sc[cc] = valid ? capped : -INFINITY;
      if (valid) mtile = fmaxf(mtile, capped);
    }
    mtile = fmaxf(mtile, __shfl_xor(mtile, 1, 64));
    mtile = fmaxf(mtile, __shfl_xor(mtile, 2, 64));
    float mnew = fmaxf(m, mtile);         // always finite (diag col always valid)
    float corr = __expf(m - mnew);        // first tile: exp(-inf)=0
    float psum = 0.f;
#pragma unroll
    for (int cc = 0; cc < 16; ++cc) {
      int c = p + 4 * cc;
      float pv = (sc[cc] > -1e30f) ? __expf(sc[cc] - mnew) : 0.f;
      Ps[r * PADF + c] = pv;
      psum += pv;
    }
    psum += __shfl_xor(psum, 1, 64);
    psum += __shfl_xor(psum, 2, 64);
    l = l * corr + psum;
    m = mnew;
#pragma unroll
    for (int i = 0; i < 16; ++i) acc[i] *= corr;
    __syncthreads();  // Ps visible to row group
    // PV: acc[p*16+i] += sum_c P[r][c] * V[c][p*16+i]
#pragma unroll 8
    for (int c = 0; c < 64; ++c) {
      float pv = Ps[r * PADF + c];
      const float4* vrow = (const float4*)&Vs[c * PADF + p * 16];
#pragma unroll
      for (int i4 = 0; i4 < 4; ++i4) {
        float4 v4 = vrow[i4];
        acc[i4 * 4 + 0] = fmaf(pv, v4.x, acc[i4 * 4 + 0]);
        acc[i4 * 4 + 1] = fmaf(pv, v4.y, acc[i4 * 4 + 1]);
        acc[i4 * 4 + 2] = fmaf(pv, v4.z, acc[i4 * 4 + 2]);
        acc[i4 * 4 + 3] = fmaf(pv, v4.w, acc[i4 * 4 + 3]);
      }
    }
  }
  const float invl = 1.f / l;
  float* obase = att + ((size_t)(b * T_ + qt0 + r) * H_ + h) * HD_ + p * 16;
#pragma unroll
  for (int i4 = 0; i4 < 4; ++i4) {
    float4 o;
    o.x = acc[i4 * 4 + 0] * invl;
    o.y = acc[i4 * 4 + 1] * invl;
    o.z = acc[i4 * 4 + 2] * invl;
    o.w = acc[i4 * 4 + 3] * invl;
    ((float4*)obase)[i4] = o;
  }
}

// ---------------- K4: output projection ----------------
__global__ __launch_bounds__(256) void oproj_kernel(
    const float* __restrict__ in, const float* __restrict__ w,
    float* __restrict__ out) {
  __shared__ float xs[PR][DIM_];
  const int tid = threadIdx.x;
  const int row0 = blockIdx.x * PR;
  {
    const float4* src = (const float4*)(in + (size_t)row0 * DIM_);
    float4* dst = (float4*)&xs[0][0];
#pragma unroll
    for (int j = 0; j < (PR * DIM_ / 4) / 256; ++j)
      dst[tid + 256 * j] = src[tid + 256 * j];
  }
  __syncthreads();
  const int wave = tid >> 6, lane = tid & 63;
  for (int u = wave; u < DIM_; u += 4) {
    const float4* w4 = (const float4*)(w + (size_t)u * DIM_);
    float acc[PR];
#pragma unroll
    for (int r = 0; r < PR; ++r) acc[r] = 0.f;
#pragma unroll
    for (int j = 0; j < DIM_ / 4 / 64; ++j) {
      float4 wv4 = w4[lane + 64 * j];
#pragma unroll
      for (int r = 0; r < PR; ++r) {
        float4 xv = ((const float4*)&xs[r][0])[lane + 64 * j];
        acc[r] = fmaf(wv4.x, xv.x, acc[r]);
        acc[r] = fmaf(wv4.y, xv.y, acc[r]);
        acc[r] = fmaf(wv4.z, xv.z, acc[r]);
        acc[r] = fmaf(wv4.w, xv.w, acc[r]);
      }
    }
#pragma unroll
    for (int r = 0; r < PR; ++r) acc[r] = wave_sum64(acc[r]);
    if (lane == 0) {
#pragma unroll
      for (int r = 0; r < PR; ++r)
        out[(size_t)(row0 + r) * DIM_ + u] = acc[r];
    }
  }
}

extern "C" void kernel_launch(void* const* d_in, const int* in_sizes, int n_in,
                              void* d_out, int out_size, void* d_ws, size_t ws_size,
                              hipStream_t stream) {
  const float* x  = (const float*)d_in[0];
  const float* wq = (const float*)d_in[1];
  const float* wk = (const float*)d_in[2];
  const float* wv = (const float*)d_in[3];
  const float* wo = (const float*)d_in[4];
  const float* qg = (const float*)d_in[5];
  const float* kg = (const float*)d_in[6];
  const float* fc = (const float*)d_in[7];
  const float* fs = (const float*)d_in[8];
  // d_in[9] = mask: causal structure is implemented directly.
  float* out = (float*)d_out;

  float* q   = (float*)d_ws;                        // NROWS_*DIM_ f32 (16 MB)
  float* kb  = q  + (size_t)NROWS_ * DIM_;          // NROWS_*HD_   (1 MB)
  float* vb  = kb + (size_t)NROWS_ * HD_;           // NROWS_*HD_   (1 MB)
  float* att = vb + (size_t)NROWS_ * HD_;           // NROWS_*DIM_  (16 MB)

  qkv_kernel<<<NROWS_ / PR, 256, 0, stream>>>(x, wq, wk, wv, q, kb, vb);
  normrope_kernel<<<NROWS_, 64, 0, stream>>>(q, kb, qg, kg, fc, fs);
  attn_kernel<<<dim3(T_ / 64, H_, B_), 256, 0, stream>>>(q, kb, vb, att);
  oproj_kernel<<<NROWS_ / PR, 256, 0, stream>>>(att, wo, out);
}

// Round 2
// 239.156 us; speedup vs baseline: 6.7912x; 6.7912x over previous
//
#include <hip/hip_runtime.h>
#include <hip/hip_bf16.h>
#include <stdint.h>
#include <math.h>

#define B_ 2
#define T_ 2048
#define DIM_ 1024
#define H_ 16
#define HD_ 64
#define NROWS_ (B_*T_)
#define NQKV 1152

typedef __bf16 bf16_t;
typedef __attribute__((ext_vector_type(8))) __bf16 bf16x8;
typedef __attribute__((ext_vector_type(4))) float f32x4;

__device__ __forceinline__ float wave_sum64(float v) {
#pragma unroll
  for (int off = 32; off > 0; off >>= 1) v += __shfl_xor(v, off, 64);
  return v;
}

// Swizzled LDS byte address for [rows][64] bf16 tiles (128B rows):
// byte = row*128 + ((col*2) ^ ((row&7)<<4)).  16B-granular XOR keeps 16B/8B
// alignment, spreads the 16-lane same-column fragment reads across 8 slots.
__device__ __forceinline__ bf16_t* swz(bf16_t* base, int row, int col) {
  return (bf16_t*)((char*)base + (row << 7) + (((col << 1) ^ ((row & 7) << 4))));
}

// ---------------- f32 -> bf16 conversion (vectorized) ----------------
__global__ __launch_bounds__(256) void cvt_bf16(const float* __restrict__ in,
                                                bf16_t* __restrict__ out, int n8) {
  for (int i = blockIdx.x * 256 + threadIdx.x; i < n8; i += gridDim.x * 256) {
    const float4* p = (const float4*)in + 2 * (size_t)i;
    float4 a = p[0], b = p[1];
    bf16x8 o;
    o[0] = (bf16_t)a.x; o[1] = (bf16_t)a.y; o[2] = (bf16_t)a.z; o[3] = (bf16_t)a.w;
    o[4] = (bf16_t)b.x; o[5] = (bf16_t)b.y; o[6] = (bf16_t)b.z; o[7] = (bf16_t)b.w;
    *(bf16x8*)(out + 8 * (size_t)i) = o;
  }
}

// ---------------- bf16 MFMA GEMM, C[m][n] = sum_k A[m][k]*Bw[n][k] ----------------
// 128x128 tile, BK=32, 4 waves (2x2), 4x4 16x16x32 frags/wave.
// Staging via global_load_lds width=16; global source pre-swizzled so the
// linear LDS holds k-slot (s ^ (row&3)) at slot s -> 4-way-spread frag reads.
template<int OUTF32>
__global__ __launch_bounds__(256) void gemm_bt(const bf16_t* __restrict__ A,
    const bf16_t* __restrict__ Bw, void* __restrict__ Cv, int N, int K) {
  __shared__ bf16_t As[128 * 32];
  __shared__ bf16_t Bs[128 * 32];
  const int tid = threadIdx.x;
  const int w = tid >> 6, lane = tid & 63;
  const int row0 = blockIdx.x * 128, col0 = blockIdx.y * 128;
  const int wm = w >> 1, wn = w & 1;
  const int rr = lane & 15, kg = lane >> 4;
  f32x4 acc[4][4];
#pragma unroll
  for (int i = 0; i < 4; ++i)
#pragma unroll
    for (int j = 0; j < 4; ++j) acc[i][j] = (f32x4){0.f, 0.f, 0.f, 0.f};
  const int srow = lane >> 2;                       // row within 16-row chunk
  const int skoff = ((lane & 3) ^ (srow & 3)) << 3; // pre-swizzled k offset (elems)
  for (int kt = 0; kt < K; kt += 32) {
    __syncthreads();
#pragma unroll
    for (int c = 0; c < 2; ++c) {
      const int chunk = 2 * w + c;
      const bf16_t* sA = A + (size_t)(row0 + chunk * 16 + srow) * K + kt + skoff;
      const bf16_t* sB = Bw + (size_t)(col0 + chunk * 16 + srow) * K + kt + skoff;
      __builtin_amdgcn_global_load_lds(
          (const __attribute__((address_space(1))) unsigned int*)(uintptr_t)sA,
          (__attribute__((address_space(3))) unsigned int*)(uintptr_t)(As + chunk * 512),
          16, 0, 0);
      __builtin_amdgcn_global_load_lds(
          (const __attribute__((address_space(1))) unsigned int*)(uintptr_t)sB,
          (__attribute__((address_space(3))) unsigned int*)(uintptr_t)(Bs + chunk * 512),
          16, 0, 0);
    }
    __syncthreads();
    bf16x8 af[4], bfv[4];
#pragma unroll
    for (int mi = 0; mi < 4; ++mi) {
      int r = 64 * wm + 16 * mi + rr;
      af[mi] = *(const bf16x8*)(As + r * 32 + ((kg ^ (r & 3)) << 3));
    }
#pragma unroll
    for (int ni = 0; ni < 4; ++ni) {
      int r = 64 * wn + 16 * ni + rr;
      bfv[ni] = *(const bf16x8*)(Bs + r * 32 + ((kg ^ (r & 3)) << 3));
    }
#pragma unroll
    for (int mi = 0; mi < 4; ++mi)
#pragma unroll
      for (int ni = 0; ni < 4; ++ni)
        acc[mi][ni] = __builtin_amdgcn_mfma_f32_16x16x32_bf16(af[mi], bfv[ni],
                                                              acc[mi][ni], 0, 0, 0);
  }
  const int crow = (lane >> 4) * 4, ccol = lane & 15;
#pragma unroll
  for (int mi = 0; mi < 4; ++mi)
#pragma unroll
    for (int ni = 0; ni < 4; ++ni)
#pragma unroll
      for (int r = 0; r < 4; ++r) {
        size_t rg = (size_t)(row0 + 64 * wm + 16 * mi + crow + r);
        size_t cg = (size_t)(col0 + 64 * wn + 16 * ni + ccol);
        if (OUTF32) ((float*)Cv)[rg * N + cg] = acc[mi][ni][r];
        else        ((bf16_t*)Cv)[rg * N + cg] = (bf16_t)acc[mi][ni][r];
      }
}

// ---------------- RMSNorm + RoPE in-place on bf16 qkv buffer ----------------
__global__ __launch_bounds__(64) void normrope(bf16_t* __restrict__ qkv,
    const float* __restrict__ qg, const float* __restrict__ kgm,
    const float* __restrict__ fc, const float* __restrict__ fs) {
  const int row = blockIdx.x;
  const int t = row & (T_ - 1);
  const int d = threadIdx.x;
  const float c = fc[t * (HD_ / 2) + (d >> 1)];
  const float s = fs[t * (HD_ / 2) + (d >> 1)];
  for (int hh = 0; hh <= H_; ++hh) {       // hh==16 -> offset 1024 = k head
    bf16_t* ptr = qkv + (size_t)row * NQKV + hh * HD_;
    float g = (hh < H_) ? qg[d] : kgm[d];
    float val = (float)ptr[d];
    float ssum = wave_sum64(val * val);
    float rms = rsqrtf(ssum * (1.f / HD_) + 1e-6f);
    val *= rms * g;
    float partner = __shfl_xor(val, 1, 64);
    float res = ((d & 1) == 0) ? (val * c - partner * s) : (partner * s + val * c);
    ptr[d] = (bf16_t)res;
  }
}

// ---------------- flash attention, bf16 MFMA ----------------
// 64-row Q tile per block, 4 waves each owning a 16-row strip. Per K/V tile:
// S strip = Q*K^T (8 mfma), softcap+mask+online softmax in-register (row
// lives in a 16-lane group; shfl_xor 1/2/4/8 reduce), P -> swizzled LDS,
// O strip += P*V (8 mfma) with V staged transposed. Heavy q-tiles first.
__global__ __launch_bounds__(256) void attn_mfma(const bf16_t* __restrict__ qkv,
                                                 bf16_t* __restrict__ att) {
  __shared__ bf16_t Qs[64 * 64];
  __shared__ bf16_t Ks[64 * 64];
  __shared__ bf16_t Vt[64 * 64];
  __shared__ bf16_t Ps[64 * 64];
  const int tid = threadIdx.x;
  const int w = tid >> 6, lane = tid & 63;
  const int qtile = (int)gridDim.x - 1 - (int)blockIdx.x;  // heavy blocks first
  const int h = blockIdx.y, b = blockIdx.z;
  const int qt0 = qtile * 64;
  const int rr = lane & 15, kg = lane >> 4;
  // stage Q (swizzled)
#pragma unroll
  for (int it = 0; it < 2; ++it) {
    int c = tid + 256 * it;
    int row = c >> 3, d0 = (c & 7) * 8;
    const bf16_t* src = qkv + (size_t)(b * T_ + qt0 + row) * NQKV + h * HD_ + d0;
    *(uint4*)swz(Qs, row, d0) = *(const uint4*)src;
  }
  float m_[4], l_[4];
  f32x4 accO[4];
#pragma unroll
  for (int i = 0; i < 4; ++i) { m_[i] = -3.0e38f; l_[i] = 0.f; accO[i] = (f32x4){0,0,0,0}; }

  for (int ct = 0; ct <= qtile; ++ct) {
    __syncthreads();   // prev PV done; also covers initial Q staging
    // stage K (swizzled rows)
#pragma unroll
    for (int it = 0; it < 2; ++it) {
      int c = tid + 256 * it;
      int row = c >> 3, d0 = (c & 7) * 8;
      const bf16_t* src = qkv + (size_t)(b * T_ + ct * 64 + row) * NQKV + DIM_ + d0;
      *(uint4*)swz(Ks, row, d0) = *(const uint4*)src;
    }
    // stage V transposed: Vt[d][t_local], wave w owns t rows [16w,16w+16)
#pragma unroll
    for (int tg = 0; tg < 2; ++tg) {
      int tl = w * 16 + tg * 8;
      const bf16_t* src = qkv + (size_t)(b * T_ + ct * 64 + tl) * NQKV + (DIM_ + HD_) + lane;
      bf16x8 vv;
#pragma unroll
      for (int j = 0; j < 8; ++j) vv[j] = src[(size_t)j * NQKV];
      *(bf16x8*)swz(Vt, lane, tl) = vv;
    }
    __syncthreads();
    // S = Q K^T  (strip rows 16w..16w+15)
    f32x4 s[4];
#pragma unroll
    for (int t = 0; t < 4; ++t) s[t] = (f32x4){0, 0, 0, 0};
#pragma unroll
    for (int k0 = 0; k0 < 2; ++k0) {
      bf16x8 aq = *(const bf16x8*)swz(Qs, 16 * w + rr, k0 * 32 + kg * 8);
#pragma unroll
      for (int t = 0; t < 4; ++t) {
        bf16x8 bk = *(const bf16x8*)swz(Ks, 16 * t + rr, k0 * 32 + kg * 8);
        s[t] = __builtin_amdgcn_mfma_f32_16x16x32_bf16(aq, bk, s[t], 0, 0, 0);
      }
    }
    // softcap 50*tanh(x/50) = 50 - 100/(exp(x/25)+1), causal mask, online softmax
    const int colb = ct * 64 + rr;
    const int rowbl = 16 * w + kg * 4;
    const int rowgb = qt0 + rowbl;
    float mx[4] = {-3.0e38f, -3.0e38f, -3.0e38f, -3.0e38f};
#pragma unroll
    for (int t = 0; t < 4; ++t)
#pragma unroll
      for (int reg = 0; reg < 4; ++reg) {
        float x = s[t][reg] * 0.125f;
        float E = __expf(x * 0.04f);
        float capped = 50.f - 100.f / (E + 1.f);
        capped = (colb + 16 * t <= rowgb + reg) ? capped : -3.0e38f;
        s[t][reg] = capped;
        mx[reg] = fmaxf(mx[reg], capped);
      }
#pragma unroll
    for (int reg = 0; reg < 4; ++reg) {
      float v = mx[reg];
      v = fmaxf(v, __shfl_xor(v, 1, 64));
      v = fmaxf(v, __shfl_xor(v, 2, 64));
      v = fmaxf(v, __shfl_xor(v, 4, 64));
      v = fmaxf(v, __shfl_xor(v, 8, 64));
      mx[reg] = v;
    }
    float corr[4], psum[4];
#pragma unroll
    for (int reg = 0; reg < 4; ++reg) {
      float mn = fmaxf(m_[reg], mx[reg]);
      corr[reg] = __expf(m_[reg] - mn);   // first tile: exp(-3e38-finite)=0
      m_[reg] = mn;
      psum[reg] = 0.f;
    }
#pragma unroll
    for (int t = 0; t < 4; ++t)
#pragma unroll
      for (int reg = 0; reg < 4; ++reg) {
        float p = __expf(s[t][reg] - m_[reg]);  // masked -> exp(-3e38)=0
        psum[reg] += p;
        *swz(Ps, rowbl + reg, 16 * t + rr) = (bf16_t)p;
      }
#pragma unroll
    for (int reg = 0; reg < 4; ++reg) {
      float v = psum[reg];
      v += __shfl_xor(v, 1, 64);
      v += __shfl_xor(v, 2, 64);
      v += __shfl_xor(v, 4, 64);
      v += __shfl_xor(v, 8, 64);
      l_[reg] = l_[reg] * corr[reg] + v;
    }
    f32x4 corrv = {corr[0], corr[1], corr[2], corr[3]};
#pragma unroll
    for (int t = 0; t < 4; ++t) accO[t] *= corrv;
    // O += P V   (Ps written/read by same wave -> per-wave DS ordering, no barrier)
#pragma unroll
    for (int k0 = 0; k0 < 2; ++k0) {
      bf16x8 ap = *(const bf16x8*)swz(Ps, 16 * w + rr, k0 * 32 + kg * 8);
#pragma unroll
      for (int dt = 0; dt < 4; ++dt) {
        bf16x8 bv = *(const bf16x8*)swz(Vt, 16 * dt + rr, k0 * 32 + kg * 8);
        accO[dt] = __builtin_amdgcn_mfma_f32_16x16x32_bf16(ap, bv, accO[dt], 0, 0, 0);
      }
    }
  }
  float linv[4];
#pragma unroll
  for (int reg = 0; reg < 4; ++reg) linv[reg] = 1.f / l_[reg];
#pragma unroll
  for (int dt = 0; dt < 4; ++dt)
#pragma unroll
    for (int reg = 0; reg < 4; ++reg) {
      size_t rg = (size_t)(b * T_ + qt0 + 16 * w + kg * 4 + reg);
      att[rg * DIM_ + h * HD_ + 16 * dt + rr] = (bf16_t)(accO[dt][reg] * linv[reg]);
    }
}

extern "C" void kernel_launch(void* const* d_in, const int* in_sizes, int n_in,
                              void* d_out, int out_size, void* d_ws, size_t ws_size,
                              hipStream_t stream) {
  const float* x   = (const float*)d_in[0];
  const float* wq  = (const float*)d_in[1];
  const float* wk  = (const float*)d_in[2];
  const float* wv  = (const float*)d_in[3];
  const float* wo  = (const float*)d_in[4];
  const float* qg  = (const float*)d_in[5];
  const float* kgm = (const float*)d_in[6];
  const float* fc  = (const float*)d_in[7];
  const float* fs  = (const float*)d_in[8];
  float* out = (float*)d_out;

  // workspace (bf16): xb 8MB | wqkvb 2.25MB | wob 2MB | qkvo 9.4MB | attb 8MB
  bf16_t* xb    = (bf16_t*)d_ws;
  bf16_t* wqkvb = xb + (size_t)NROWS_ * DIM_;
  bf16_t* wob   = wqkvb + (size_t)NQKV * DIM_;
  bf16_t* qkvo  = wob + (size_t)DIM_ * DIM_;
  bf16_t* attb  = qkvo + (size_t)NROWS_ * NQKV;

  cvt_bf16<<<2048, 256, 0, stream>>>(x, xb, NROWS_ * DIM_ / 8);
  cvt_bf16<<<512, 256, 0, stream>>>(wq, wqkvb, DIM_ * DIM_ / 8);
  cvt_bf16<<<32, 256, 0, stream>>>(wk, wqkvb + (size_t)DIM_ * DIM_, HD_ * DIM_ / 8);
  cvt_bf16<<<32, 256, 0, stream>>>(wv, wqkvb + (size_t)(DIM_ + HD_) * DIM_, HD_ * DIM_ / 8);
  cvt_bf16<<<512, 256, 0, stream>>>(wo, wob, DIM_ * DIM_ / 8);

  gemm_bt<0><<<dim3(NROWS_ / 128, NQKV / 128), 256, 0, stream>>>(xb, wqkvb, qkvo, NQKV, DIM_);
  normrope<<<NROWS_, 64, 0, stream>>>(qkvo, qg, kgm, fc, fs);
  attn_mfma<<<dim3(T_ / 64, H_, B_), 256, 0, stream>>>(qkvo, attb);
  gemm_bt<1><<<dim3(NROWS_ / 128, DIM_ / 128), 256, 0, stream>>>(attb, wob, out, DIM_, DIM_);
}

// Round 3
// 152.752 us; speedup vs baseline: 10.6327x; 1.5656x over previous
//
#include <hip/hip_runtime.h>
#include <hip/hip_bf16.h>
#include <stdint.h>
#include <math.h>

#define B_ 2
#define T_ 2048
#define DIM_ 1024
#define H_ 16
#define HD_ 64
#define NROWS_ (B_*T_)
#define NQKV 1152

typedef __bf16 bf16_t;
typedef __attribute__((ext_vector_type(8))) __bf16 bf16x8;
typedef __attribute__((ext_vector_type(4))) __bf16 bf16x4;
typedef __attribute__((ext_vector_type(4))) float f32x4;

__device__ __forceinline__ float wave_sum64(float v) {
#pragma unroll
  for (int off = 32; off > 0; off >>= 1) v += __shfl_xor(v, off, 64);
  return v;
}

// Swizzled LDS byte address for [rows][64] bf16 tiles (128B rows):
// byte = row*128 + ((col*2) ^ ((row&7)<<4)). 16B-granular XOR keeps 16B/8B
// alignment; spreads same-column fragment reads across 8 slots.
__device__ __forceinline__ bf16_t* swz(bf16_t* base, int row, int col) {
  return (bf16_t*)((char*)base + (row << 7) + (((col << 1) ^ ((row & 7) << 4))));
}

// ---------------- f32 -> bf16 conversion (vectorized) ----------------
__global__ __launch_bounds__(256) void cvt_bf16(const float* __restrict__ in,
                                                bf16_t* __restrict__ out, int n8) {
  for (int i = blockIdx.x * 256 + threadIdx.x; i < n8; i += gridDim.x * 256) {
    const float4* p = (const float4*)in + 2 * (size_t)i;
    float4 a = p[0], b = p[1];
    bf16x8 o;
    o[0] = (bf16_t)a.x; o[1] = (bf16_t)a.y; o[2] = (bf16_t)a.z; o[3] = (bf16_t)a.w;
    o[4] = (bf16_t)b.x; o[5] = (bf16_t)b.y; o[6] = (bf16_t)b.z; o[7] = (bf16_t)b.w;
    *(bf16x8*)(out + 8 * (size_t)i) = o;
  }
}

// ---------------- bf16 MFMA GEMM, C[m][n] = sum_k A[m][k]*Bw[n][k] ----------------
template<int OUTF32>
__global__ __launch_bounds__(256) void gemm_bt(const bf16_t* __restrict__ A,
    const bf16_t* __restrict__ Bw, void* __restrict__ Cv, int N, int K) {
  __shared__ bf16_t As[128 * 32];
  __shared__ bf16_t Bs[128 * 32];
  const int tid = threadIdx.x;
  const int w = tid >> 6, lane = tid & 63;
  const int row0 = blockIdx.x * 128, col0 = blockIdx.y * 128;
  const int wm = w >> 1, wn = w & 1;
  const int rr = lane & 15, kg = lane >> 4;
  f32x4 acc[4][4];
#pragma unroll
  for (int i = 0; i < 4; ++i)
#pragma unroll
    for (int j = 0; j < 4; ++j) acc[i][j] = (f32x4){0.f, 0.f, 0.f, 0.f};
  const int srow = lane >> 2;
  const int skoff = ((lane & 3) ^ (srow & 3)) << 3;
  for (int kt = 0; kt < K; kt += 32) {
    __syncthreads();
#pragma unroll
    for (int c = 0; c < 2; ++c) {
      const int chunk = 2 * w + c;
      const bf16_t* sA = A + (size_t)(row0 + chunk * 16 + srow) * K + kt + skoff;
      const bf16_t* sB = Bw + (size_t)(col0 + chunk * 16 + srow) * K + kt + skoff;
      __builtin_amdgcn_global_load_lds(
          (const __attribute__((address_space(1))) unsigned int*)(uintptr_t)sA,
          (__attribute__((address_space(3))) unsigned int*)(uintptr_t)(As + chunk * 512),
          16, 0, 0);
      __builtin_amdgcn_global_load_lds(
          (const __attribute__((address_space(1))) unsigned int*)(uintptr_t)sB,
          (__attribute__((address_space(3))) unsigned int*)(uintptr_t)(Bs + chunk * 512),
          16, 0, 0);
    }
    __syncthreads();
    bf16x8 af[4], bfv[4];
#pragma unroll
    for (int mi = 0; mi < 4; ++mi) {
      int r = 64 * wm + 16 * mi + rr;
      af[mi] = *(const bf16x8*)(As + r * 32 + ((kg ^ (r & 3)) << 3));
    }
#pragma unroll
    for (int ni = 0; ni < 4; ++ni) {
      int r = 64 * wn + 16 * ni + rr;
      bfv[ni] = *(const bf16x8*)(Bs + r * 32 + ((kg ^ (r & 3)) << 3));
    }
#pragma unroll
    for (int mi = 0; mi < 4; ++mi)
#pragma unroll
      for (int ni = 0; ni < 4; ++ni)
        acc[mi][ni] = __builtin_amdgcn_mfma_f32_16x16x32_bf16(af[mi], bfv[ni],
                                                              acc[mi][ni], 0, 0, 0);
  }
  const int crow = (lane >> 4) * 4, ccol = lane & 15;
#pragma unroll
  for (int mi = 0; mi < 4; ++mi)
#pragma unroll
    for (int ni = 0; ni < 4; ++ni)
#pragma unroll
      for (int r = 0; r < 4; ++r) {
        size_t rg = (size_t)(row0 + 64 * wm + 16 * mi + crow + r);
        size_t cg = (size_t)(col0 + 64 * wn + 16 * ni + ccol);
        if (OUTF32) ((float*)Cv)[rg * N + cg] = acc[mi][ni][r];
        else        ((bf16_t*)Cv)[rg * N + cg] = (bf16_t)acc[mi][ni][r];
      }
}

// ---------------- RMSNorm + RoPE in-place (4 waves/row, heads in parallel) ----------------
__global__ __launch_bounds__(256) void normrope(bf16_t* __restrict__ qkv,
    const float* __restrict__ qg, const float* __restrict__ kgm,
    const float* __restrict__ fc, const float* __restrict__ fs) {
  const int row = blockIdx.x;
  const int w = threadIdx.x >> 6, d = threadIdx.x & 63;
  const int t = row & (T_ - 1);
  const float c = fc[t * (HD_ / 2) + (d >> 1)];
  const float s = fs[t * (HD_ / 2) + (d >> 1)];
  for (int hh = w; hh <= H_; hh += 4) {   // hh==16 -> k head at offset 1024
    bf16_t* ptr = qkv + (size_t)row * NQKV + hh * HD_;
    float g = (hh < H_) ? qg[d] : kgm[d];
    float val = (float)ptr[d];
    float ssum = wave_sum64(val * val);
    float rms = rsqrtf(ssum * (1.f / HD_) + 1e-6f);
    val *= rms * g;
    float partner = __shfl_xor(val, 1, 64);
    float res = ((d & 1) == 0) ? (val * c - partner * s) : (partner * s + val * c);
    ptr[d] = (bf16_t)res;
  }
}

// ---------------- flash attention, bf16 MFMA, MQA-aware ----------------
// Block = (qtile, head-pair, b), 512 threads / 8 waves. Waves 0-3 -> head h0
// strips, 4-7 -> head h1. K/V staged once per pair, reg-double-buffered
// (loads for ct+1 issued before compute of ct). Swapped QK^T (mfma(K,Q)) so
// each lane holds one query's scores with 4 contiguous keys per reg-quad:
// P-writes are 4x ds_write_b64, softmax sum = in-lane + 2 shfls. Softcap
// bounds scores to +-50 => fixed-max softmax p = exp(34 - 100/(E+1)), no
// online max / rescale. Diagonal tile peeled (mask only there).
__global__ __launch_bounds__(512) void attn_mfma(const bf16_t* __restrict__ qkv,
                                                 bf16_t* __restrict__ att) {
  __shared__ bf16_t Qs[2][64 * 64];
  __shared__ bf16_t Ks[64 * 64];
  __shared__ bf16_t Vt[64 * 64];
  __shared__ bf16_t Ps[2][64 * 64];
  __shared__ float Ls[2][64];
  const int tid = threadIdx.x;
  const int w = tid >> 6, lane = tid & 63;
  const int qtile = (int)gridDim.x - 1 - (int)blockIdx.x;  // heavy blocks first
  const int h0 = blockIdx.y * 2, b = blockIdx.z;
  const int qt0 = qtile * 64;
  const size_t bT = (size_t)b * T_;
  const int rr = lane & 15, kg = lane >> 4;
  const int hw = w >> 2, sw = w & 3;
  // stage Q for both heads (swizzled)
#pragma unroll
  for (int it = 0; it < 2; ++it) {
    int c = tid + 512 * it;
    int hh = c >> 9, row = (c >> 3) & 63, d0 = (c & 7) * 8;
    const bf16_t* src = qkv + (size_t)(bT + qt0 + row) * NQKV + (h0 + hh) * HD_ + d0;
    *(uint4*)swz(Qs[hh], row, d0) = *(const uint4*)src;
  }
  const int krow = tid >> 3, kd0 = (tid & 7) * 8;  // K staging map (512 thr = 64x64)
  const int vt0 = w * 8;                           // V gather: wave w -> t rows [8w,8w+8)
  uint4 kreg;
  bf16x8 vreg;
  {
    const bf16_t* ksrc = qkv + (size_t)(bT + krow) * NQKV + DIM_ + kd0;
    kreg = *(const uint4*)ksrc;
    const bf16_t* vsrc = qkv + (size_t)(bT + vt0) * NQKV + (DIM_ + HD_) + lane;
#pragma unroll
    for (int j = 0; j < 8; ++j) vreg[j] = vsrc[(size_t)j * NQKV];
  }
  f32x4 accO[4];
  float l_ = 0.f;
#pragma unroll
  for (int i = 0; i < 4; ++i) accO[i] = (f32x4){0, 0, 0, 0};

#define ATTN_TILE(CT, DIAG)                                                     \
  do {                                                                          \
    __syncthreads();                                                            \
    *(uint4*)swz(Ks, krow, kd0) = kreg;                                         \
    *(bf16x8*)swz(Vt, lane, vt0) = vreg;                                        \
    __syncthreads();                                                            \
    if (!(DIAG)) { /* prefetch next tile into regs; lands during compute */     \
      const bf16_t* ksrc =                                                      \
          qkv + (size_t)(bT + ((CT) + 1) * 64 + krow) * NQKV + DIM_ + kd0;      \
      kreg = *(const uint4*)ksrc;                                               \
      const bf16_t* vsrc =                                                      \
          qkv + (size_t)(bT + ((CT) + 1) * 64 + vt0) * NQKV + (DIM_ + HD_) + lane; \
      _Pragma("unroll") for (int j = 0; j < 8; ++j) vreg[j] =                   \
          vsrc[(size_t)j * NQKV];                                               \
    }                                                                           \
    f32x4 s[4];                                                                 \
    _Pragma("unroll") for (int t = 0; t < 4; ++t) s[t] = (f32x4){0, 0, 0, 0};   \
    _Pragma("unroll") for (int k0 = 0; k0 < 2; ++k0) {                          \
      bf16x8 bq = *(const bf16x8*)swz(Qs[hw], 16 * sw + rr, k0 * 32 + kg * 8);  \
      _Pragma("unroll") for (int t = 0; t < 4; ++t) {                           \
        bf16x8 ak = *(const bf16x8*)swz(Ks, 16 * t + rr, k0 * 32 + kg * 8);     \
        s[t] = __builtin_amdgcn_mfma_f32_16x16x32_bf16(ak, bq, s[t], 0, 0, 0);  \
      }                                                                         \
    }                                                                           \
    float psum = 0.f;                                                           \
    _Pragma("unroll") for (int t = 0; t < 4; ++t) {                             \
      bf16x4 pk;                                                                \
      _Pragma("unroll") for (int reg = 0; reg < 4; ++reg) {                     \
        float E = __expf(s[t][reg] * 0.005f);                                   \
        float r = __builtin_amdgcn_rcpf(E + 1.f);                               \
        float p = __expf(fmaf(-100.f, r, 34.f));                                \
        if (DIAG) {                                                             \
          bool valid = (16 * t + 4 * kg + reg) <= (16 * sw + rr);               \
          p = valid ? p : 0.f;                                                  \
        }                                                                       \
        psum += p;                                                              \
        pk[reg] = (bf16_t)p;                                                    \
      }                                                                         \
      *(bf16x4*)swz(Ps[hw], 16 * sw + rr, 16 * t + 4 * kg) = pk;                \
    }                                                                           \
    psum += __shfl_xor(psum, 16, 64);                                           \
    psum += __shfl_xor(psum, 32, 64);                                           \
    l_ += psum;                                                                 \
    _Pragma("unroll") for (int k0 = 0; k0 < 2; ++k0) {                          \
      bf16x8 ap = *(const bf16x8*)swz(Ps[hw], 16 * sw + rr, k0 * 32 + kg * 8);  \
      _Pragma("unroll") for (int dt = 0; dt < 4; ++dt) {                        \
        bf16x8 bv = *(const bf16x8*)swz(Vt, 16 * dt + rr, k0 * 32 + kg * 8);    \
        accO[dt] =                                                              \
            __builtin_amdgcn_mfma_f32_16x16x32_bf16(ap, bv, accO[dt], 0, 0, 0); \
      }                                                                         \
    }                                                                           \
  } while (0)

  for (int ct = 0; ct < qtile; ++ct) ATTN_TILE(ct, false);
  ATTN_TILE(qtile, true);
#undef ATTN_TILE

  // distribute l (indexed by query=rr) to output layout (query=4kg+reg)
  if (kg == 0) Ls[hw][16 * sw + rr] = l_;
  f32x4 l4 = *(f32x4*)&Ls[hw][16 * sw + 4 * kg];
  f32x4 linv;
#pragma unroll
  for (int reg = 0; reg < 4; ++reg) linv[reg] = 1.f / l4[reg];
#pragma unroll
  for (int dt = 0; dt < 4; ++dt)
#pragma unroll
    for (int reg = 0; reg < 4; ++reg) {
      size_t rg = (size_t)(bT + qt0 + 16 * sw + 4 * kg + reg);
      att[rg * DIM_ + (h0 + hw) * HD_ + 16 * dt + rr] =
          (bf16_t)(accO[dt][reg] * linv[reg]);
    }
}

extern "C" void kernel_launch(void* const* d_in, const int* in_sizes, int n_in,
                              void* d_out, int out_size, void* d_ws, size_t ws_size,
                              hipStream_t stream) {
  const float* x   = (const float*)d_in[0];
  const float* wq  = (const float*)d_in[1];
  const float* wk  = (const float*)d_in[2];
  const float* wv  = (const float*)d_in[3];
  const float* wo  = (const float*)d_in[4];
  const float* qg  = (const float*)d_in[5];
  const float* kgm = (const float*)d_in[6];
  const float* fc  = (const float*)d_in[7];
  const float* fs  = (const float*)d_in[8];
  float* out = (float*)d_out;

  bf16_t* xb    = (bf16_t*)d_ws;
  bf16_t* wqkvb = xb + (size_t)NROWS_ * DIM_;
  bf16_t* wob   = wqkvb + (size_t)NQKV * DIM_;
  bf16_t* qkvo  = wob + (size_t)DIM_ * DIM_;
  bf16_t* attb  = qkvo + (size_t)NROWS_ * NQKV;

  cvt_bf16<<<2048, 256, 0, stream>>>(x, xb, NROWS_ * DIM_ / 8);
  cvt_bf16<<<512, 256, 0, stream>>>(wq, wqkvb, DIM_ * DIM_ / 8);
  cvt_bf16<<<32, 256, 0, stream>>>(wk, wqkvb + (size_t)DIM_ * DIM_, HD_ * DIM_ / 8);
  cvt_bf16<<<32, 256, 0, stream>>>(wv, wqkvb + (size_t)(DIM_ + HD_) * DIM_, HD_ * DIM_ / 8);
  cvt_bf16<<<512, 256, 0, stream>>>(wo, wob, DIM_ * DIM_ / 8);

  gemm_bt<0><<<dim3(NROWS_ / 128, NQKV / 128), 256, 0, stream>>>(xb, wqkvb, qkvo, NQKV, DIM_);
  normrope<<<NROWS_, 256, 0, stream>>>(qkvo, qg, kgm, fc, fs);
  attn_mfma<<<dim3(T_ / 64, H_ / 2, B_), 512, 0, stream>>>(qkvo, attb);
  gemm_bt<1><<<dim3(NROWS_ / 128, DIM_ / 128), 256, 0, stream>>>(attb, wob, out, DIM_, DIM_);
}